// Round 23
// baseline (58.594 us; speedup 1.0000x reference)
//
#include <hip/hip_runtime.h>
#include <hip/hip_bf16.h>
#include <stdint.h>

#define N_ROWS 16384
#define O_ROWS 1024
#define K_DIM  512

typedef __bf16 bf16x8 __attribute__((ext_vector_type(8)));
typedef float  f32x4  __attribute__((ext_vector_type(4)));

__device__ __forceinline__ ushort f2bfu(float f) {
    __bf16 h = (__bf16)f;
    return __builtin_bit_cast(ushort, h);
}

#define BAR_LGKM()  do {                                        \
    asm volatile("s_waitcnt lgkmcnt(0)" ::: "memory");          \
    __builtin_amdgcn_s_barrier();                               \
} while (0)

// ---------------------------------------------------------------------------
// Round 23: A staged as RAW F32 via global_load_lds (async DMA), BK=32,
// A double-buffered (2x32KB) + counted vmcnt(4) -> true T4 pipelining.
//  - staging phase ~zero wave work (4 DMA issues); f32->bf16 cvt + xsq sumsq
//    move INTO the MFMA phase (VALU pipe overlaps MFMA, m114).
//  - DMA dest is linear (m104); swizzle via PRE-SWIZZLED SOURCE (m173):
//    16B unit u_src = u ^ (row&7); frag reads apply the same XOR -> <=2-way.
//  - B (mean, small) reg-staged bf16 per kt-PAIR with r16's exact proven
//    [128][64] swizzled geometry; B global loads sit before DMA-issue so the
//    compiler's wait for them drains only the CURRENT A batch (kt+1 stays
//    in flight).
//  - 256x128 tile, 512 thr, 8 waves (4x2), 64x64 wave tiles, acc 4x4.
//  - LDS 80KB -> 2 blocks/CU. XCD swizzle, extended-K epilogue, unroll 1.
//  - A-sumsq from f32 frags on wc==0 waves (reduce over hi at end);
//    B-sumsq in staging (reduce over q4 group).
// ---------------------------------------------------------------------------
__global__ __launch_bounds__(512) void quadra_kernel(
    const float* __restrict__ x, const float* __restrict__ mean,
    float* __restrict__ out)
{
    __shared__ float  sAf[2][256 * 32];   // A f32, 2 x 32 KiB (src-swizzled)
    __shared__ ushort sB[128 * 64];       // B bf16 (-2*mean), 16 KiB, r16 swz

    const int bid  = blockIdx.x;                // 0..511
    const int t    = (bid & 7) * 64 + (bid >> 3);
    const int brow = (t >> 3) * 256;
    const int bcol = (t & 7) * 128;

    const int tid  = threadIdx.x;
    const int lane = tid & 63;
    const int wid  = tid >> 6;                  // 0..7
    const int wr = wid >> 1, wc = wid & 1;      // 4x2 wave grid, 64x64 out
    const int cl = lane & 15, hi = lane >> 4;

    f32x4 acc[4][4] = {};

    // --- A DMA geometry: wave wid owns rows [wid*32, wid*32+32), 4 calls.
    // dest (linear): byte wid*4096 + c*1024 + lane*16
    // src: row = wid*32 + c*8 + (lane>>3); unit u_src = (lane&7) ^ (row&7)
    const int dr = lane >> 3, du = lane & 7;
    const float* gdma[4];
    #pragma unroll
    for (int c = 0; c < 4; ++c) {
        const int row = wid * 32 + c * 8 + dr;
        gdma[c] = x + (size_t)(brow + row) * K_DIM + ((du ^ (row & 7)) * 4);
    }
    const int dmaoff = wid * 4096 + lane * 16;

    // --- B staging geometry: row = tid>>2 (0..127), q4 = tid&3; per kt-pair
    // thread loads 16 f32 at k = pair*64 + q4*16.
    const int rbw = tid >> 2;
    const int q4  = tid & 3;
    const float* gB = mean + (size_t)(bcol + rbw) * K_DIM + q4 * 16;

    float asq[4] = {0.f, 0.f, 0.f, 0.f};
    float bsq = 0.f;

    // prologue: DMA A(kt=0) into buf 0
    #pragma unroll
    for (int c = 0; c < 4; ++c)
        __builtin_amdgcn_global_load_lds(
            (const __attribute__((address_space(1))) void*)(gdma[c]),
            (__attribute__((address_space(3))) void*)
                ((char*)&sAf[0][0] + dmaoff + c * 1024), 16, 0, 0);

    #pragma unroll 1
    for (int kt = 0; kt < 16; ++kt) {
        const int cur = kt & 1;

        // --- even kt: stage B pair kt/2 (r16 geometry). B loads are the
        // newest vm ops here, so the compiler's wait for them drains only
        // the current A batch (already ~arrived), not the next one.
        if ((kt & 1) == 0) {
            const float* p = gB + (kt >> 1) * 64;
            f32x4 v0 = *(const f32x4*)(p);
            f32x4 v1 = *(const f32x4*)(p + 4);
            f32x4 v2 = *(const f32x4*)(p + 8);
            f32x4 v3 = *(const f32x4*)(p + 12);

            bsq += v0[0]*v0[0] + v0[1]*v0[1] + v0[2]*v0[2] + v0[3]*v0[3]
                 + v1[0]*v1[0] + v1[1]*v1[1] + v1[2]*v1[2] + v1[3]*v1[3]
                 + v2[0]*v2[0] + v2[1]*v2[1] + v2[2]*v2[2] + v2[3]*v2[3]
                 + v3[0]*v3[0] + v3[1]*v3[1] + v3[2]*v3[2] + v3[3]*v3[3];

            bf16x8 c0, c1;
            c0[0] = (__bf16)(v0[0] * -2.0f); c0[1] = (__bf16)(v0[1] * -2.0f);
            c0[2] = (__bf16)(v0[2] * -2.0f); c0[3] = (__bf16)(v0[3] * -2.0f);
            c0[4] = (__bf16)(v1[0] * -2.0f); c0[5] = (__bf16)(v1[1] * -2.0f);
            c0[6] = (__bf16)(v1[2] * -2.0f); c0[7] = (__bf16)(v1[3] * -2.0f);
            c1[0] = (__bf16)(v2[0] * -2.0f); c1[1] = (__bf16)(v2[1] * -2.0f);
            c1[2] = (__bf16)(v2[2] * -2.0f); c1[3] = (__bf16)(v2[3] * -2.0f);
            c1[4] = (__bf16)(v3[0] * -2.0f); c1[5] = (__bf16)(v3[1] * -2.0f);
            c1[6] = (__bf16)(v3[2] * -2.0f); c1[7] = (__bf16)(v3[3] * -2.0f);

            const int swz = (rbw & 7) << 4;
            *(bf16x8*)(sB + rbw * 64 + (((q4 * 32)      ^ swz) >> 1)) = c0;
            *(bf16x8*)(sB + rbw * 64 + (((q4 * 32 + 16) ^ swz) >> 1)) = c1;
        }

        // --- issue DMA for kt+1 into the other buffer; counted wait keeps
        // it in flight across the barrier + MFMA phase.
        if (kt < 15) {
            #pragma unroll
            for (int c = 0; c < 4; ++c)
                __builtin_amdgcn_global_load_lds(
                    (const __attribute__((address_space(1))) void*)
                        (gdma[c] + (kt + 1) * 32),
                    (__attribute__((address_space(3))) void*)
                        ((char*)&sAf[cur ^ 1][0] + dmaoff + c * 1024), 16, 0, 0);
            asm volatile("s_waitcnt vmcnt(4)" ::: "memory");   // kt's batch done
        } else {
            asm volatile("s_waitcnt vmcnt(0)" ::: "memory");
        }
        BAR_LGKM();   // A[cur] DMA + B writes visible

        // --- MFMA phase: A f32 frags (cvt + sumsq in-phase), B bf16 frags
        const float* bufA = &sAf[cur][0];
        bf16x8 a[4], b[4];
        #pragma unroll
        for (int m = 0; m < 4; ++m) {
            const int row = wr * 64 + m * 16 + cl;
            const float* bp = bufA + row * 32;
            f32x4 v0 = *(const f32x4*)(bp + ((hi * 2    ) ^ (row & 7)) * 4);
            f32x4 v1 = *(const f32x4*)(bp + ((hi * 2 + 1) ^ (row & 7)) * 4);
            if (wc == 0)
                asq[m] += v0[0]*v0[0] + v0[1]*v0[1] + v0[2]*v0[2] + v0[3]*v0[3]
                        + v1[0]*v1[0] + v1[1]*v1[1] + v1[2]*v1[2] + v1[3]*v1[3];
            bf16x8 cv;
            cv[0] = (__bf16)v0[0]; cv[1] = (__bf16)v0[1];
            cv[2] = (__bf16)v0[2]; cv[3] = (__bf16)v0[3];
            cv[4] = (__bf16)v1[0]; cv[5] = (__bf16)v1[1];
            cv[6] = (__bf16)v1[2]; cv[7] = (__bf16)v1[3];
            a[m] = cv;
        }
        #pragma unroll
        for (int n = 0; n < 4; ++n) {
            const int row = wc * 64 + n * 16 + cl;
            const int rb  = ((kt & 1) * 64 + hi * 16) ^ ((row & 7) << 4);
            b[n] = *(const bf16x8*)(sB + row * 64 + (rb >> 1));
        }
        #pragma unroll
        for (int m = 0; m < 4; ++m)
            #pragma unroll
            for (int n = 0; n < 4; ++n)
                acc[m][n] = __builtin_amdgcn_mfma_f32_16x16x32_bf16(
                    a[m], b[n], acc[m][n], 0, 0, 0);

        BAR_LGKM();   // reads of A[cur]/sB drained; next kt may overwrite
    }

    // --- extended K-tile (aliased into sAf[0], dead after loop):
    //   sAe[row(256)] = [xsq, 1, 0 x30]   sBe[row(128)] = [1, msq, 0 x30]
    ushort* sAe = (ushort*)&sAf[0][0];    // 16 KB
    ushort* sBe = sAe + 256 * 32;         //  8 KB (still within sAf[0])
    if (wc == 0) {
        #pragma unroll
        for (int m = 0; m < 4; ++m) {
            float sa = asq[m];
            sa += __shfl_xor(sa, 16);
            sa += __shfl_xor(sa, 32);
            const int row = wr * 64 + m * 16 + cl;
            uint4 w4 = {0u, 0u, 0u, 0u};
            if (hi == 0) w4.x = (uint32_t)f2bfu(sa) | (0x3F80u << 16); // [xsq,1]
            *(uint4*)(sAe + row * 32 + hi * 8) = w4;
        }
    }
    {
        float sb = bsq;
        sb += __shfl_xor(sb, 1);
        sb += __shfl_xor(sb, 2);
        uint4 w4 = {0u, 0u, 0u, 0u};
        if (q4 == 0) w4.x = 0x3F80u | ((uint32_t)f2bfu(sb) << 16);    // [1,msq]
        *(uint4*)(sBe + rbw * 32 + q4 * 8) = w4;
    }
    BAR_LGKM();

    {   // extra MFMA: adds xsq[r] + msq[o] into every accumulator element
        bf16x8 a[4], b[4];
        #pragma unroll
        for (int m = 0; m < 4; ++m)
            a[m] = *(const bf16x8*)(sAe + (wr*64 + m*16 + cl) * 32 + hi * 8);
        #pragma unroll
        for (int n = 0; n < 4; ++n)
            b[n] = *(const bf16x8*)(sBe + (wc*64 + n*16 + cl) * 32 + hi * 8);
        #pragma unroll
        for (int m = 0; m < 4; ++m)
            #pragma unroll
            for (int n = 0; n < 4; ++n)
                acc[m][n] = __builtin_amdgcn_mfma_f32_16x16x32_bf16(
                    a[m], b[n], acc[m][n], 0, 0, 0);
    }

    // epilogue: C/D layout col = lane&15, row = (lane>>4)*4 + j
    #pragma unroll
    for (int m = 0; m < 4; ++m) {
        #pragma unroll
        for (int j = 0; j < 4; ++j) {
            const int grow = brow + wr*64 + m*16 + hi*4 + j;
            float* orow = out + (size_t)grow * O_ROWS + bcol + wc*64 + cl;
            #pragma unroll
            for (int n = 0; n < 4; ++n)
                orow[n * 16] = rsqrtf(acc[m][n][j]);
        }
    }
}

extern "C" void kernel_launch(void* const* d_in, const int* in_sizes, int n_in,
                              void* d_out, int out_size, void* d_ws, size_t ws_size,
                              hipStream_t stream) {
    const float* x    = (const float*)d_in[0];
    const float* mean = (const float*)d_in[1];
    float* out = (float*)d_out;

    quadra_kernel<<<dim3((N_ROWS / 256) * (O_ROWS / 128)), 512, 0, stream>>>(
        x, mean, out);
}